// Round 1
// baseline (127.624 us; speedup 1.0000x reference)
//
#include <hip/hip_runtime.h>

#define DIM 256  // 2^8 amplitudes

// 5 layer matrices, 4x4 complex each, row-major M[r*4+c]
__device__ float2 g_M[5 * 16];

__device__ inline float2 cmul(float2 a, float2 b) {
    return make_float2(a.x * b.x - a.y * b.y, a.x * b.y + a.y * b.x);
}
__device__ inline float2 cadd(float2 a, float2 b) {
    return make_float2(a.x + b.x, a.y + b.y);
}

// ---------------- setup: build the 5 SU(4) gate matrices ----------------

__device__ void mat_u3(float t, float p, float l, float2* U) {
    float s, c;
    sincosf(0.5f * t, &s, &c);
    float sp, cp, sl, cl, spl, cpl;
    sincosf(p, &sp, &cp);
    sincosf(l, &sl, &cl);
    sincosf(p + l, &spl, &cpl);
    U[0] = make_float2(c, 0.f);
    U[1] = make_float2(-cl * s, -sl * s);   // -e^{il} s
    U[2] = make_float2(cp * s, sp * s);     //  e^{ip} s
    U[3] = make_float2(cpl * c, spl * c);   //  e^{i(p+l)} c
}
__device__ void mat_ry(float t, float2* U) {
    float s, c;
    sincosf(0.5f * t, &s, &c);
    U[0] = make_float2(c, 0.f); U[1] = make_float2(-s, 0.f);
    U[2] = make_float2(s, 0.f); U[3] = make_float2(c, 0.f);
}
__device__ void mat_rz(float t, float2* U) {
    float s, c;
    sincosf(0.5f * t, &s, &c);
    U[0] = make_float2(c, -s); U[1] = make_float2(0.f, 0.f);
    U[2] = make_float2(0.f, 0.f); U[3] = make_float2(c, s);
}
__device__ void mat_I2(float2* U) {
    U[0] = make_float2(1.f, 0.f); U[1] = make_float2(0.f, 0.f);
    U[2] = make_float2(0.f, 0.f); U[3] = make_float2(1.f, 0.f);
}
__device__ void kron4(const float2* A, const float2* B, float2* K) {
    for (int i0 = 0; i0 < 2; ++i0)
        for (int i1 = 0; i1 < 2; ++i1)
            for (int j0 = 0; j0 < 2; ++j0)
                for (int j1 = 0; j1 < 2; ++j1)
                    K[(2 * i0 + i1) * 4 + (2 * j0 + j1)] = cmul(A[i0 * 2 + j0], B[i1 * 2 + j1]);
}
__device__ void mm4(const float2* A, const float2* B, float2* C) {
    for (int r = 0; r < 4; ++r)
        for (int c = 0; c < 4; ++c) {
            float2 acc = make_float2(0.f, 0.f);
            for (int k = 0; k < 4; ++k) acc = cadd(acc, cmul(A[r * 4 + k], B[k * 4 + c]));
            C[r * 4 + c] = acc;
        }
}
__device__ void swap_rows(float2* M, int r1, int r2) {
    for (int c = 0; c < 4; ++c) {
        float2 t = M[r1 * 4 + c]; M[r1 * 4 + c] = M[r2 * 4 + c]; M[r2 * 4 + c] = t;
    }
}

__global__ void qsvdd_setup(const float* __restrict__ w) {
    int l = threadIdx.x;
    if (l >= 5) return;
    const float* p = w + l * 15;
    float2 A[4], Bm[4], K[16], M[16], T[16];
    mat_u3(p[0], p[1], p[2], A);
    mat_u3(p[3], p[4], p[5], Bm);
    kron4(A, Bm, M);
    swap_rows(M, 2, 3);                       // CNOT01 @ M
    mat_ry(p[6], A); mat_rz(p[7], Bm);
    kron4(A, Bm, K); mm4(K, M, T);
    swap_rows(T, 1, 3);                       // CNOT10 @ M
    mat_ry(p[8], A); mat_I2(Bm);
    kron4(A, Bm, K); mm4(K, T, M);
    swap_rows(M, 2, 3);                       // CNOT01 @ M
    mat_u3(p[9], p[10], p[11], A);
    mat_u3(p[12], p[13], p[14], Bm);
    kron4(A, Bm, K); mm4(K, M, T);
    for (int i = 0; i < 16; ++i) g_M[l * 16 + i] = T[i];
}

// ---------------- main: statevector sim, one wave per batch element ----------------

// wire w lives at bit (7-w) of the amplitude index (wire 0 = MSB).
// 25 gate applications: layer of each, and bit positions (pa = 7-a, pb = 7-b).
__constant__ int c_npairs[5] = {8, 8, 4, 4, 1};
__constant__ int c_pa[25] = {7,5,3,1,6,4,2,0, 7,5,3,1,6,4,2,0, 5,1,7,3, 5,1,7,3, 5};
__constant__ int c_pb[25] = {6,4,2,0,5,3,1,7, 6,4,2,0,5,3,1,7, 3,7,5,1, 3,7,5,1, 1};

__device__ inline int swz(int i) { return i ^ (i >> 4); }  // bank-spread swizzle (bijective)

__device__ inline void cmad(float2& a, float2 m, float2 v) {
    a.x = fmaf(m.x, v.x, a.x);
    a.x = fmaf(-m.y, v.y, a.x);
    a.y = fmaf(m.x, v.y, a.y);
    a.y = fmaf(m.y, v.x, a.y);
}

__global__ __launch_bounds__(256) void qsvdd_main(const float* __restrict__ x,
                                                  float* __restrict__ out) {
    __shared__ float2 S[4][DIM];
    const int tid = threadIdx.x;
    const int wid = tid >> 6;
    const int lane = tid & 63;
    const long e = (long)blockIdx.x * 4 + wid;
    float2* st = S[wid];

    // ---- amplitude embedding (normalize) ----
    float4 xv = *reinterpret_cast<const float4*>(x + e * DIM + lane * 4);
    float ss = xv.x * xv.x + xv.y * xv.y + xv.z * xv.z + xv.w * xv.w;
#pragma unroll
    for (int off = 32; off; off >>= 1) ss += __shfl_xor(ss, off, 64);
    const float inv = 1.0f / sqrtf(ss);
    const int b4 = lane * 4;
    st[swz(b4 + 0)] = make_float2(xv.x * inv, 0.f);
    st[swz(b4 + 1)] = make_float2(xv.y * inv, 0.f);
    st[swz(b4 + 2)] = make_float2(xv.z * inv, 0.f);
    st[swz(b4 + 3)] = make_float2(xv.w * inv, 0.f);
    __syncthreads();

    // ---- 25 two-qubit gate applications ----
    int app = 0;
    for (int l = 0; l < 5; ++l) {
        float2 M[16];
#pragma unroll
        for (int i = 0; i < 16; ++i) M[i] = g_M[l * 16 + i];
        const int np = c_npairs[l];
        for (int pr = 0; pr < np; ++pr, ++app) {
            const int pa = c_pa[app], pb = c_pb[app];
            const int lo = (pa < pb) ? pa : pb;
            const int hi = (pa < pb) ? pb : pa;
            int i = ((lane >> lo) << (lo + 1)) | (lane & ((1 << lo) - 1));
            i = ((i >> hi) << (hi + 1)) | (i & ((1 << hi) - 1));
            const int i00 = i;
            const int i01 = i | (1 << pb);
            const int i10 = i | (1 << pa);
            const int i11 = i01 | (1 << pa);
            float2 v[4];
            v[0] = st[swz(i00)];
            v[1] = st[swz(i01)];
            v[2] = st[swz(i10)];
            v[3] = st[swz(i11)];
            float2 n[4];
#pragma unroll
            for (int r = 0; r < 4; ++r) {
                float2 acc = make_float2(0.f, 0.f);
#pragma unroll
                for (int c = 0; c < 4; ++c) cmad(acc, M[r * 4 + c], v[c]);
                n[r] = acc;
            }
            st[swz(i00)] = n[0];
            st[swz(i01)] = n[1];
            st[swz(i10)] = n[2];
            st[swz(i11)] = n[3];
            __syncthreads();
        }
    }

    // ---- expectation values: X,Y,Z on wire 2 (bit 5) and wire 6 (bit 1) ----
    float acc[6] = {0.f, 0.f, 0.f, 0.f, 0.f, 0.f};
#pragma unroll
    for (int wi = 0; wi < 2; ++wi) {
        const int p = (wi == 0) ? 5 : 1;
#pragma unroll
        for (int k = 0; k < 2; ++k) {
            const int pidx = lane + 64 * k;  // 7-bit pair index
            const int i0 = ((pidx >> p) << (p + 1)) | (pidx & ((1 << p) - 1));
            const int i1 = i0 | (1 << p);
            const float2 s0 = st[swz(i0)];
            const float2 s1 = st[swz(i1)];
            acc[wi * 3 + 0] += s0.x * s1.x + s0.y * s1.y;             // Re(conj(s0) s1)
            acc[wi * 3 + 1] += s0.x * s1.y - s0.y * s1.x;             // Im(conj(s0) s1)
            acc[wi * 3 + 2] += s0.x * s0.x + s0.y * s0.y - s1.x * s1.x - s1.y * s1.y;
        }
    }
    acc[0] *= 2.f; acc[1] *= 2.f; acc[3] *= 2.f; acc[4] *= 2.f;
#pragma unroll
    for (int k = 0; k < 6; ++k) {
#pragma unroll
        for (int off = 32; off; off >>= 1) acc[k] += __shfl_xor(acc[k], off, 64);
    }
    if (lane == 0) {
        float* o = out + e * 6;
        o[0] = acc[0]; o[1] = acc[1]; o[2] = acc[2];
        o[3] = acc[3]; o[4] = acc[4]; o[5] = acc[5];
    }
}

extern "C" void kernel_launch(void* const* d_in, const int* in_sizes, int n_in,
                              void* d_out, int out_size, void* d_ws, size_t ws_size,
                              hipStream_t stream) {
    const float* x = (const float*)d_in[0];
    const float* w = (const float*)d_in[1];
    float* out = (float*)d_out;
    const int B = in_sizes[0] / DIM;  // 32768

    hipLaunchKernelGGL(qsvdd_setup, dim3(1), dim3(64), 0, stream, w);
    hipLaunchKernelGGL(qsvdd_main, dim3(B / 4), dim3(256), 0, stream, x, out);
}

// Round 2
// 112.807 us; speedup vs baseline: 1.1313x; 1.1313x over previous
//
#include <hip/hip_runtime.h>

#define DIM 256  // 2^8 amplitudes

// 5 layer matrices, 4x4 complex each, row-major M[r*4+c]
__device__ float2 g_M[5 * 16];

__device__ inline float2 cmulc(float2 a, float2 b) {
    return make_float2(a.x * b.x - a.y * b.y, a.x * b.y + a.y * b.x);
}
__device__ inline float2 caddc(float2 a, float2 b) {
    return make_float2(a.x + b.x, a.y + b.y);
}

// ---------------- setup: build the 5 SU(4) gate matrices ----------------

__device__ void mat_u3(float t, float p, float l, float2* U) {
    float s, c;
    sincosf(0.5f * t, &s, &c);
    float sp, cp, sl, cl, spl, cpl;
    sincosf(p, &sp, &cp);
    sincosf(l, &sl, &cl);
    sincosf(p + l, &spl, &cpl);
    U[0] = make_float2(c, 0.f);
    U[1] = make_float2(-cl * s, -sl * s);
    U[2] = make_float2(cp * s, sp * s);
    U[3] = make_float2(cpl * c, spl * c);
}
__device__ void mat_ry(float t, float2* U) {
    float s, c;
    sincosf(0.5f * t, &s, &c);
    U[0] = make_float2(c, 0.f); U[1] = make_float2(-s, 0.f);
    U[2] = make_float2(s, 0.f); U[3] = make_float2(c, 0.f);
}
__device__ void mat_rz(float t, float2* U) {
    float s, c;
    sincosf(0.5f * t, &s, &c);
    U[0] = make_float2(c, -s); U[1] = make_float2(0.f, 0.f);
    U[2] = make_float2(0.f, 0.f); U[3] = make_float2(c, s);
}
__device__ void mat_I2(float2* U) {
    U[0] = make_float2(1.f, 0.f); U[1] = make_float2(0.f, 0.f);
    U[2] = make_float2(0.f, 0.f); U[3] = make_float2(1.f, 0.f);
}
__device__ void kron4(const float2* A, const float2* B, float2* K) {
    for (int i0 = 0; i0 < 2; ++i0)
        for (int i1 = 0; i1 < 2; ++i1)
            for (int j0 = 0; j0 < 2; ++j0)
                for (int j1 = 0; j1 < 2; ++j1)
                    K[(2 * i0 + i1) * 4 + (2 * j0 + j1)] = cmulc(A[i0 * 2 + j0], B[i1 * 2 + j1]);
}
__device__ void mm4(const float2* A, const float2* B, float2* C) {
    for (int r = 0; r < 4; ++r)
        for (int c = 0; c < 4; ++c) {
            float2 acc = make_float2(0.f, 0.f);
            for (int k = 0; k < 4; ++k) acc = caddc(acc, cmulc(A[r * 4 + k], B[k * 4 + c]));
            C[r * 4 + c] = acc;
        }
}
__device__ void swap_rows(float2* M, int r1, int r2) {
    for (int c = 0; c < 4; ++c) {
        float2 t = M[r1 * 4 + c]; M[r1 * 4 + c] = M[r2 * 4 + c]; M[r2 * 4 + c] = t;
    }
}

__global__ void qsvdd_setup(const float* __restrict__ w) {
    int l = threadIdx.x;
    if (l >= 5) return;
    const float* p = w + l * 15;
    float2 A[4], Bm[4], K[16], M[16], T[16];
    mat_u3(p[0], p[1], p[2], A);
    mat_u3(p[3], p[4], p[5], Bm);
    kron4(A, Bm, M);
    swap_rows(M, 2, 3);                       // CNOT01 @ M
    mat_ry(p[6], A); mat_rz(p[7], Bm);
    kron4(A, Bm, K); mm4(K, M, T);
    swap_rows(T, 1, 3);                       // CNOT10 @ M
    mat_ry(p[8], A); mat_I2(Bm);
    kron4(A, Bm, K); mm4(K, T, M);
    swap_rows(M, 2, 3);                       // CNOT01 @ M
    mat_u3(p[9], p[10], p[11], A);
    mat_u3(p[12], p[13], p[14], Bm);
    kron4(A, Bm, K); mm4(K, M, T);
    for (int i = 0; i < 16; ++i) g_M[l * 16 + i] = T[i];
}

// ---------------- main: register-resident statevector, one wave per element ----------------
//
// Amplitude index a (8 bits, wire w = bit 7-w). Layout: 2 "local" bits live in
// the per-lane register index (v[0..3]); 6 bits live in the lane id. Gates act
// on the two local bits (pure register 4x4 complex matvec, M in SGPRs); bit
// swaps (local<->lane) use ds_bpermute with precomputed partner addresses.
// Hand-derived schedule: 25 gates + 40 bit-swaps, no barriers, no LDS tiles.

__device__ __forceinline__ float rfl(float x) {
    return __int_as_float(__builtin_amdgcn_readfirstlane(__float_as_int(x)));
}

__device__ __forceinline__ float2 fsel(bool c, float2 a, float2 b) {
    return make_float2(c ? a.x : b.x, c ? a.y : b.y);
}

__device__ __forceinline__ void cmadsv(float2& a, float mx, float my, const float2 v) {
    a.x = fmaf(mx, v.x, a.x);
    a.x = fmaf(-my, v.y, a.x);
    a.y = fmaf(mx, v.y, a.y);
    a.y = fmaf(my, v.x, a.y);
}

// 4x4 complex matvec on the quadruple; IP = local slot of first tensor factor
// (high bit of the 4-index), IQ = slot of second factor.
template <int IP, int IQ>
__device__ __forceinline__ void gate4(float2* v, const float2* M) {
    constexpr int mp = 1 << IP, mq = 1 << IQ;
    const float2 a0 = v[0], a1 = v[mq], a2 = v[mp], a3 = v[mp | mq];
    float2 n[4];
#pragma unroll
    for (int r = 0; r < 4; ++r) {
        float2 acc = make_float2(0.f, 0.f);
        cmadsv(acc, M[r * 4 + 0].x, M[r * 4 + 0].y, a0);
        cmadsv(acc, M[r * 4 + 1].x, M[r * 4 + 1].y, a1);
        cmadsv(acc, M[r * 4 + 2].x, M[r * 4 + 2].y, a2);
        cmadsv(acc, M[r * 4 + 3].x, M[r * 4 + 3].y, a3);
        n[r] = acc;
    }
    v[0] = n[0]; v[mq] = n[1]; v[mp] = n[2]; v[mp | mq] = n[3];
}

// swap local (register) bit R with a lane bit; pb = own lane bit, ba = bpermute
// byte-address of partner lane (= (lane ^ mask) << 2).
template <int R>
__device__ __forceinline__ void bswap(float2* v, bool pb, int ba) {
    constexpr int m = 1 << R;
#pragma unroll
    for (int j = 0; j < 4; ++j) {
        if (j & m) continue;
        const int j1 = j | m;
        float2 s = fsel(pb, v[j], v[j1]);
        float2 r;
        r.x = __int_as_float(__builtin_amdgcn_ds_bpermute(ba, __float_as_int(s.x)));
        r.y = __int_as_float(__builtin_amdgcn_ds_bpermute(ba, __float_as_int(s.y)));
        v[j] = fsel(pb, r, v[j]);
        v[j1] = fsel(pb, v[j1], r);
    }
}

__global__ __launch_bounds__(256) void qsvdd_main(const float* __restrict__ x,
                                                  float* __restrict__ out) {
    const int lane = threadIdx.x & 63;
    const long e = (long)blockIdx.x * 4 + (threadIdx.x >> 6);

    // partner addresses + own-bit predicates for the 6 lane bits
    const int ba0 = ((lane ^ 1) << 2), ba1 = ((lane ^ 2) << 2), ba2 = ((lane ^ 4) << 2);
    const int ba3 = ((lane ^ 8) << 2), ba4 = ((lane ^ 16) << 2), ba5 = ((lane ^ 32) << 2);
    const bool p0 = lane & 1, p1 = lane & 2, p2 = lane & 4;
    const bool p3 = lane & 8, p4 = lane & 16, p5 = lane & 32;

    // ---- amplitude embedding: a = lane*4 + j  (local bits = logical 1:0) ----
    float4 xv = *reinterpret_cast<const float4*>(x + (e << 8) + (lane << 2));
    float ss = xv.x * xv.x + xv.y * xv.y + xv.z * xv.z + xv.w * xv.w;
#pragma unroll
    for (int off = 32; off; off >>= 1) ss += __shfl_xor(ss, off, 64);
    const float inv = rsqrtf(ss);
    float2 v[4];
    v[0] = make_float2(xv.x * inv, 0.f);
    v[1] = make_float2(xv.y * inv, 0.f);
    v[2] = make_float2(xv.z * inv, 0.f);
    v[3] = make_float2(xv.w * inv, 0.f);

    float2 Mm[16];
#define LOADM(L)                                                              \
    {                                                                         \
        const float* gm = reinterpret_cast<const float*>(g_M) + (L) * 32;     \
        _Pragma("unroll") for (int i = 0; i < 16; ++i) {                      \
            Mm[i].x = rfl(gm[2 * i]);                                         \
            Mm[i].y = rfl(gm[2 * i + 1]);                                     \
        }                                                                     \
    }

    // ---- hand-derived schedule: slots s=(s0,s1) track logical bits ----
    LOADM(0);
    // A1: (1,0),(3,2),(5,4),(7,6)
    gate4<1, 0>(v, Mm);                           // (1,0)  s=(0,1)
    bswap<0>(v, p0, ba0); bswap<1>(v, p1, ba1);   // s=(2,3)
    gate4<1, 0>(v, Mm);                           // (3,2)
    bswap<0>(v, p2, ba2); bswap<1>(v, p3, ba3);   // s=(4,5)
    gate4<1, 0>(v, Mm);                           // (5,4)
    bswap<0>(v, p4, ba4); bswap<1>(v, p5, ba5);   // s=(6,7)
    gate4<1, 0>(v, Mm);                           // (7,6)
    // B1: (6,5),(4,3),(2,1),(0,7)
    bswap<1>(v, p5, ba5);                         // s=(6,5)
    gate4<0, 1>(v, Mm);                           // (6,5)
    bswap<0>(v, p4, ba4); bswap<1>(v, p3, ba3);   // s=(4,3)
    gate4<0, 1>(v, Mm);                           // (4,3)
    bswap<0>(v, p2, ba2); bswap<1>(v, p1, ba1);   // s=(2,1)
    gate4<0, 1>(v, Mm);                           // (2,1)
    bswap<0>(v, p0, ba0); bswap<1>(v, p5, ba5);   // s=(0,7)
    gate4<0, 1>(v, Mm);                           // (0,7)
    LOADM(1);
    // A2
    bswap<1>(v, p5, ba5);                         // s=(0,1)
    gate4<1, 0>(v, Mm);                           // (1,0)
    bswap<0>(v, p0, ba0); bswap<1>(v, p1, ba1);   // s=(2,3)
    gate4<1, 0>(v, Mm);                           // (3,2)
    bswap<0>(v, p2, ba2); bswap<1>(v, p3, ba3);   // s=(4,5)
    gate4<1, 0>(v, Mm);                           // (5,4)
    bswap<0>(v, p4, ba4); bswap<1>(v, p5, ba5);   // s=(6,7)
    gate4<1, 0>(v, Mm);                           // (7,6)
    // B2 (identical swap pattern to B1)
    bswap<1>(v, p5, ba5);                         // s=(6,5)
    gate4<0, 1>(v, Mm);                           // (6,5)
    bswap<0>(v, p4, ba4); bswap<1>(v, p3, ba3);   // s=(4,3)
    gate4<0, 1>(v, Mm);                           // (4,3)
    bswap<0>(v, p2, ba2); bswap<1>(v, p1, ba1);   // s=(2,1)
    gate4<0, 1>(v, Mm);                           // (2,1)
    bswap<0>(v, p0, ba0); bswap<1>(v, p5, ba5);   // s=(0,7)
    gate4<0, 1>(v, Mm);                           // (0,7)
    LOADM(2);
    // A3: (1,7),(5,3)   [lane positions now: p=(2,3,4,5,6,1)]
    bswap<0>(v, p5, ba5);                         // s=(1,7)
    gate4<0, 1>(v, Mm);                           // (1,7)
    bswap<0>(v, p1, ba1); bswap<1>(v, p3, ba3);   // s=(3,5)
    gate4<1, 0>(v, Mm);                           // (5,3)
    // B3: (7,5),(3,1)   [p=(2,1,4,7,6,0)]
    bswap<0>(v, p3, ba3);                         // s=(7,5)
    gate4<0, 1>(v, Mm);                           // (7,5)
    bswap<0>(v, p3, ba3); bswap<1>(v, p1, ba1);   // s=(3,1)
    gate4<0, 1>(v, Mm);                           // (3,1)
    LOADM(3);
    // A4: (1,7),(5,3)   [p=(2,5,4,7,6,0)]
    bswap<0>(v, p3, ba3);                         // s=(7,1)
    gate4<1, 0>(v, Mm);                           // (1,7)
    bswap<0>(v, p3, ba3); bswap<1>(v, p1, ba1);   // s=(3,5)
    gate4<1, 0>(v, Mm);                           // (5,3)
    // B4 (same pattern as B3)
    bswap<0>(v, p3, ba3);                         // s=(7,5)
    gate4<0, 1>(v, Mm);                           // (7,5)
    bswap<0>(v, p3, ba3); bswap<1>(v, p1, ba1);   // s=(3,1)
    gate4<0, 1>(v, Mm);                           // (3,1)
    LOADM(4);
    // L3: (5,1)   [p=(2,5,4,7,6,0)]
    bswap<0>(v, p1, ba1);                         // s=(5,1)
    gate4<0, 1>(v, Mm);                           // (5,1)

    // ---- expvals: bit 5 (wire 2) at slot 0, bit 1 (wire 6) at slot 1 ----
    float acc[6];
    {
        // wire 2: pairs (v0,v1), (v2,v3)
        const float2 a = v[0], b = v[1], c = v[2], d = v[3];
        acc[0] = (a.x * b.x + a.y * b.y) + (c.x * d.x + c.y * d.y);
        acc[1] = (a.x * b.y - a.y * b.x) + (c.x * d.y - c.y * d.x);
        acc[2] = (a.x * a.x + a.y * a.y) - (b.x * b.x + b.y * b.y)
               + (c.x * c.x + c.y * c.y) - (d.x * d.x + d.y * d.y);
        // wire 6: pairs (v0,v2), (v1,v3)
        acc[3] = (a.x * c.x + a.y * c.y) + (b.x * d.x + b.y * d.y);
        acc[4] = (a.x * c.y - a.y * c.x) + (b.x * d.y - b.y * d.x);
        acc[5] = (a.x * a.x + a.y * a.y) - (c.x * c.x + c.y * c.y)
               + (b.x * b.x + b.y * b.y) - (d.x * d.x + d.y * d.y);
    }
    acc[0] *= 2.f; acc[1] *= 2.f; acc[3] *= 2.f; acc[4] *= 2.f;
#pragma unroll
    for (int k = 0; k < 6; ++k) {
#pragma unroll
        for (int off = 32; off; off >>= 1) acc[k] += __shfl_xor(acc[k], off, 64);
    }
    if (lane == 0) {
        float* o = out + e * 6;
        o[0] = acc[0]; o[1] = acc[1]; o[2] = acc[2];
        o[3] = acc[3]; o[4] = acc[4]; o[5] = acc[5];
    }
}

extern "C" void kernel_launch(void* const* d_in, const int* in_sizes, int n_in,
                              void* d_out, int out_size, void* d_ws, size_t ws_size,
                              hipStream_t stream) {
    const float* x = (const float*)d_in[0];
    const float* w = (const float*)d_in[1];
    float* out = (float*)d_out;
    const int B = in_sizes[0] / DIM;  // 32768

    hipLaunchKernelGGL(qsvdd_setup, dim3(1), dim3(64), 0, stream, w);
    hipLaunchKernelGGL(qsvdd_main, dim3(B / 4), dim3(256), 0, stream, x, out);
}